// Round 4
// baseline (198.391 us; speedup 1.0000x reference)
//
#include <hip/hip_runtime.h>

#define D 2048
#define M 512

// Tuned NS coefficients, equioscillation on sv interval [0.48,1.52]:
// step1 -> delta 0.2188, step2 -> 0.03633, step3 -> 0.00099
#define CA1 1.7509363f
#define CB1 0.5353890f
#define CA2 1.5424421f
#define CB2 0.5060067f
#define CA3 1.5011558f
#define CB3 0.5001653f

typedef unsigned short u16;
typedef unsigned int u32;
typedef __attribute__((ext_vector_type(8))) short bf16x8;
typedef __attribute__((ext_vector_type(4))) float f32x4;

__device__ inline u16 f2bf(float f) {
    union { float f; unsigned u; } v; v.f = f;
    unsigned r = v.u + 0x7fffu + ((v.u >> 16) & 1u);  // RNE
    return (u16)(r >> 16);
}
__device__ inline float bf2f(u16 h) {
    union { float f; unsigned u; } v; v.u = ((unsigned)h) << 16;
    return v.f;
}

__device__ inline void store_split(u16* __restrict__ H, u16* __restrict__ L,
                                   size_t idx, float v) {
    const u16 h = f2bf(v);
    H[idx] = h;
    L[idx] = f2bf(v - bf2f(h));
}

// One 128-k chunk: load all 16 fragments, then 12 MFMAs.
__device__ inline void mmchunk(const u16* __restrict__ ah, const u16* __restrict__ al,
                               const u16* __restrict__ bh, const u16* __restrict__ bl,
                               f32x4& a1, f32x4& a2) {
    bf16x8 fah[4], fal[4], fbh[4], fbl[4];
    #pragma unroll
    for (int i = 0; i < 4; ++i) {
        fah[i] = *(const bf16x8*)(ah + 32 * i);
        fal[i] = *(const bf16x8*)(al + 32 * i);
        fbh[i] = *(const bf16x8*)(bh + 32 * i);
        fbl[i] = *(const bf16x8*)(bl + 32 * i);
    }
    #pragma unroll
    for (int i = 0; i < 4; ++i) {
        a1 = __builtin_amdgcn_mfma_f32_16x16x32_bf16(fah[i], fbh[i], a1, 0, 0, 0);
        a2 = __builtin_amdgcn_mfma_f32_16x16x32_bf16(fah[i], fbl[i], a2, 0, 0, 0);
        a2 = __builtin_amdgcn_mfma_f32_16x16x32_bf16(fal[i], fbh[i], a2, 0, 0, 0);
    }
}

// per-wave K-range fragment MACs (K multiple of 128)
__device__ inline void mm_ks(const u16* __restrict__ aHi,
                             const u16* __restrict__ aLo, int lda,
                             const u16* __restrict__ bHi,
                             const u16* __restrict__ bLo, int ldb,
                             int K, int lm, int lq, f32x4& a1, f32x4& a2) {
    const u16* ah = aHi + (size_t)lm * lda + lq * 8;
    const u16* al = aLo + (size_t)lm * lda + lq * 8;
    const u16* bh = bHi + (size_t)lm * ldb + lq * 8;
    const u16* bl = bLo + (size_t)lm * ldb + lq * 8;
    #pragma unroll 4
    for (int k = 0; k < K; k += 128)
        mmchunk(ah + k, al + k, bh + k, bl + k, a1, a2);
}

// 32x32 tile of U·V^T per 512-thread block: 8 waves = 4 quadrants x 2 K-halves.
__device__ inline void tile32(const u16* __restrict__ Uh, const u16* __restrict__ Ul, int lda,
                              const u16* __restrict__ Vh, const u16* __restrict__ Vl, int ldb,
                              int K, int i0, int j0, int t, float* red,
                              float val[2], int row[2], int col[2]) {
    const int w = t >> 6, lane = t & 63;
    const int lm = lane & 15, lq = lane >> 4;
    const int q = w >> 1, kh = w & 1;
    const int qi = q >> 1, qj = q & 1;
    const int Kh = K >> 1;
    const size_t ko = (size_t)kh * Kh;
    f32x4 a1 = {0.f, 0.f, 0.f, 0.f}, a2 = {0.f, 0.f, 0.f, 0.f};
    mm_ks(Uh + (size_t)(i0 + 16 * qi) * lda + ko, Ul + (size_t)(i0 + 16 * qi) * lda + ko, lda,
          Vh + (size_t)(j0 + 16 * qj) * ldb + ko, Vl + (size_t)(j0 + 16 * qj) * ldb + ko, ldb,
          Kh, lm, lq, a1, a2);
    const f32x4 s = a1 + a2;
    #pragma unroll
    for (int r = 0; r < 4; ++r) red[w * 256 + (lq * 4 + r) * 16 + lm] = s[r];
    __syncthreads();
    #pragma unroll
    for (int e = 0; e < 2; ++e) {
        const int ee = t + e * 512;
        const int qq = ee >> 8, p = ee & 255;
        val[e] = red[qq * 512 + p] + red[qq * 512 + 256 + p];
        row[e] = i0 + 16 * (qq >> 1) + (p >> 4);
        col[e] = j0 + 16 * (qq & 1) + (p & 15);
    }
}

// LDS swizzle for the fused gram staging
__device__ inline int swz(int c) { return (((c >> 2) ^ c) & 3) << 3; }

// ---- d1: fused transpose + gram: G0 = X^T X from X fp32 directly.
// 256 blocks x 512 thr. 128-k chunks (16 iters, 2 MFMA-triples/iter), LDS
// transposed [c][k^swz(c)] double-buffered (64 KB). j0==0 blocks also emit
// Xhi/Xlo row-major. Emits G0 hi/lo and C1 = CA1*I - CB1*G0.
__global__ __launch_bounds__(512) void gram_fx(
    const float* __restrict__ X,
    u16* __restrict__ Gh, u16* __restrict__ Gl,
    u16* __restrict__ Ch, u16* __restrict__ Cl,
    u16* __restrict__ Xhi, u16* __restrict__ Xlo) {
    __shared__ __align__(16) char smem[65536];
    u32* LT = (u32*)smem;          // 4 regions of 4096 u32: A:buf, B:2+buf
    float* red = (float*)smem;     // reused for the final reduce

    const int i0 = (blockIdx.x >> 4) * 32, j0 = (blockIdx.x & 15) * 32;
    const int t = threadIdx.x;
    const int w = t >> 6, lane = t & 63;
    const int lm = lane & 15, lq = lane >> 4;
    const int q = w >> 1, kh = w & 1;
    const int qi = q >> 1, qj = q & 1;
    const bool emitX = (j0 == 0);

    const int r = t >> 3;            // 0..63 (k within chunk, +64 for 2nd row)
    const int c4 = (t & 7) * 4;      // 0..28 (col within stripe)

    const float* pa = X + (size_t)r * M + i0 + c4;
    const float* pb = X + (size_t)r * M + j0 + c4;
    float4 fA0 = *(const float4*)pa;
    float4 fA1 = *(const float4*)(pa + (size_t)64 * M);
    float4 fB0 = *(const float4*)pb;
    float4 fB1 = *(const float4*)(pb + (size_t)64 * M);

    f32x4 a1 = {0.f, 0.f, 0.f, 0.f}, a2 = {0.f, 0.f, 0.f, 0.f};
    int buf = 0;

    for (int k0 = 0; k0 < D; k0 += 128) {
        u32 pkA0[4], pkA1[4], pkB0[4], pkB1[4];
        {
            const float va0[4] = {fA0.x, fA0.y, fA0.z, fA0.w};
            const float va1[4] = {fA1.x, fA1.y, fA1.z, fA1.w};
            const float vb0[4] = {fB0.x, fB0.y, fB0.z, fB0.w};
            const float vb1[4] = {fB1.x, fB1.y, fB1.z, fB1.w};
            #pragma unroll
            for (int e = 0; e < 4; ++e) {
                union { float f; u32 u; } u0, u1, u2, u3, h0, h1, h2, h3;
                u0.f = va0[e]; u1.f = va1[e]; u2.f = vb0[e]; u3.f = vb1[e];
                h0.u = u0.u & 0xFFFF0000u;  // truncated hi
                h1.u = u1.u & 0xFFFF0000u;
                h2.u = u2.u & 0xFFFF0000u;
                h3.u = u3.u & 0xFFFF0000u;
                pkA0[e] = h0.u | f2bf(va0[e] - h0.f);
                pkA1[e] = h1.u | f2bf(va1[e] - h1.f);
                pkB0[e] = h2.u | f2bf(vb0[e] - h2.f);
                pkB1[e] = h3.u | f2bf(vb1[e] - h3.f);
            }
        }
        u32* A0 = LT + buf * 4096;
        u32* B0 = LT + (2 + buf) * 4096;
        #pragma unroll
        for (int e = 0; e < 4; ++e) {
            const int c = c4 + e;
            const int rk = r ^ swz(c);
            A0[c * 128 + rk] = pkA0[e];
            A0[c * 128 + rk + 64] = pkA1[e];
            B0[c * 128 + rk] = pkB0[e];
            B0[c * 128 + rk + 64] = pkB1[e];
        }
        if (emitX) {  // row-major bf16 split of X (this block's stripe)
            uint2 hw, lw;
            hw.x = (pkA0[0] >> 16) | (pkA0[1] & 0xFFFF0000u);
            hw.y = (pkA0[2] >> 16) | (pkA0[3] & 0xFFFF0000u);
            lw.x = (pkA0[0] & 0xFFFFu) | (pkA0[1] << 16);
            lw.y = (pkA0[2] & 0xFFFFu) | (pkA0[3] << 16);
            *(uint2*)(Xhi + (size_t)(k0 + r) * M + i0 + c4) = hw;
            *(uint2*)(Xlo + (size_t)(k0 + r) * M + i0 + c4) = lw;
            hw.x = (pkA1[0] >> 16) | (pkA1[1] & 0xFFFF0000u);
            hw.y = (pkA1[2] >> 16) | (pkA1[3] & 0xFFFF0000u);
            lw.x = (pkA1[0] & 0xFFFFu) | (pkA1[1] << 16);
            lw.y = (pkA1[2] & 0xFFFFu) | (pkA1[3] << 16);
            *(uint2*)(Xhi + (size_t)(k0 + r + 64) * M + i0 + c4) = hw;
            *(uint2*)(Xlo + (size_t)(k0 + r + 64) * M + i0 + c4) = lw;
        }
        __syncthreads();
        if (k0 + 128 < D) {
            fA0 = *(const float4*)(pa + (size_t)(k0 + 128) * M);
            fA1 = *(const float4*)(pa + (size_t)(k0 + 192) * M);
            fB0 = *(const float4*)(pb + (size_t)(k0 + 128) * M);
            fB1 = *(const float4*)(pb + (size_t)(k0 + 192) * M);
        }
        #pragma unroll
        for (int ks = 0; ks < 64; ks += 32) {
            const int ca = 16 * qi + lm, cb = 16 * qj + lm;
            const int kb = kh * 64 + ks + lq * 8;
            const u32* ap = A0 + ca * 128 + (kb ^ swz(ca));
            const u32* bp = B0 + cb * 128 + (kb ^ swz(cb));
            u32 au[8], bu[8];
            *(uint4*)(au) = *(const uint4*)(ap);
            *(uint4*)(au + 4) = *(const uint4*)(ap + 4);
            *(uint4*)(bu) = *(const uint4*)(bp);
            *(uint4*)(bu + 4) = *(const uint4*)(bp + 4);
            u32 ahp[4], alp[4], bhp[4], blp[4];
            #pragma unroll
            for (int e = 0; e < 4; ++e) {
                ahp[e] = (au[2 * e] >> 16) | (au[2 * e + 1] & 0xFFFF0000u);
                alp[e] = (au[2 * e] & 0xFFFFu) | (au[2 * e + 1] << 16);
                bhp[e] = (bu[2 * e] >> 16) | (bu[2 * e + 1] & 0xFFFF0000u);
                blp[e] = (bu[2 * e] & 0xFFFFu) | (bu[2 * e + 1] << 16);
            }
            const bf16x8 fah = *(const bf16x8*)ahp;
            const bf16x8 fal = *(const bf16x8*)alp;
            const bf16x8 fbh = *(const bf16x8*)bhp;
            const bf16x8 fbl = *(const bf16x8*)blp;
            a1 = __builtin_amdgcn_mfma_f32_16x16x32_bf16(fah, fbh, a1, 0, 0, 0);
            a2 = __builtin_amdgcn_mfma_f32_16x16x32_bf16(fah, fbl, a2, 0, 0, 0);
            a2 = __builtin_amdgcn_mfma_f32_16x16x32_bf16(fal, fbh, a2, 0, 0, 0);
        }
        buf ^= 1;
    }

    __syncthreads();
    const f32x4 s = a1 + a2;
    #pragma unroll
    for (int e = 0; e < 4; ++e) red[w * 256 + (lq * 4 + e) * 16 + lm] = s[e];
    __syncthreads();
    #pragma unroll
    for (int e = 0; e < 2; ++e) {
        const int ee = t + e * 512;
        const int qq = ee >> 8, p = ee & 255;
        const float g = red[qq * 512 + p] + red[qq * 512 + 256 + p];
        const int row = i0 + 16 * (qq >> 1) + (p >> 4);
        const int col = j0 + 16 * (qq & 1) + (p & 15);
        const size_t idx = (size_t)row * M + col;
        u16 h = f2bf(g);
        Gh[idx] = h; Gl[idx] = f2bf(g - bf2f(h));
        const float c = (row == col ? CA1 : 0.0f) - CB1 * g;
        h = f2bf(c);
        Ch[idx] = h; Cl[idx] = f2bf(c - bf2f(h));
    }
}

// ---- dual stage: blocks [0,1024): O = U·C (D-space X-chain, C symmetric);
// blocks [1024,1280): S = G·G (M-space gram square). All K=512.
__global__ __launch_bounds__(512) void dualSX(
    const u16* __restrict__ Gh, const u16* __restrict__ Gl,
    u16* __restrict__ Sh, u16* __restrict__ Sl,
    const u16* __restrict__ Uh, const u16* __restrict__ Ul,
    const u16* __restrict__ Vh, const u16* __restrict__ Vl,
    u16* __restrict__ Oh, u16* __restrict__ Ol) {
    __shared__ float red[2048];
    const int bid = (int)blockIdx.x;
    float val[2]; int row[2], col[2];
    if (bid < 1024) {
        const int i0 = (bid >> 4) * 32, j0 = (bid & 15) * 32;
        tile32(Uh, Ul, M, Vh, Vl, M, 512, i0, j0, threadIdx.x, red, val, row, col);
        #pragma unroll
        for (int e = 0; e < 2; ++e)
            store_split(Oh, Ol, (size_t)row[e] * M + col[e], val[e]);
    } else {
        const int b = bid - 1024;
        const int i0 = (b >> 4) * 32, j0 = (b & 15) * 32;
        tile32(Gh, Gl, M, Gh, Gl, M, 512, i0, j0, threadIdx.x, red, val, row, col);
        #pragma unroll
        for (int e = 0; e < 2; ++e)
            store_split(Sh, Sl, (size_t)row[e] * M + col[e], val[e]);
    }
}

// ---- poly step: W=U·V^T; P = cA*Ge + cB*Se + cC*W; store P (opt), C = a*I - b*P.
__global__ __launch_bounds__(512) void poly32(
    const u16* __restrict__ Uh, const u16* __restrict__ Ul,
    const u16* __restrict__ Vh, const u16* __restrict__ Vl,
    const u16* __restrict__ Geh, const u16* __restrict__ Gel,
    const u16* __restrict__ Seh, const u16* __restrict__ Sel,
    u16* __restrict__ Ph, u16* __restrict__ Pl,
    u16* __restrict__ Ch, u16* __restrict__ Cl,
    const float cA, const float cB, const float cC,
    const float a, const float b, const int writeP) {
    __shared__ float red[2048];
    const int i0 = ((int)blockIdx.x >> 4) * 32, j0 = ((int)blockIdx.x & 15) * 32;
    float val[2]; int row[2], col[2];
    tile32(Uh, Ul, M, Vh, Vl, M, 512, i0, j0, threadIdx.x, red, val, row, col);
    #pragma unroll
    for (int e = 0; e < 2; ++e) {
        const size_t idx = (size_t)row[e] * M + col[e];
        const float p = cA * (bf2f(Geh[idx]) + bf2f(Gel[idx]))
                      + cB * (bf2f(Seh[idx]) + bf2f(Sel[idx]))
                      + cC * val[e];
        if (writeP) {
            store_split(Ph, Pl, idx, p);
        }
        const float c = (row[e] == col[e] ? a : 0.0f) - b * p;
        const u16 h2 = f2bf(c);
        Ch[idx] = h2; Cl[idx] = f2bf(c - bf2f(h2));
    }
}

// ---- final: out = U·C (fp32 out), U = X2 split [2048][512], C symmetric.
__global__ __launch_bounds__(512) void xb32(
    const u16* __restrict__ Xhi, const u16* __restrict__ Xlo,
    const u16* __restrict__ Bh, const u16* __restrict__ Bl,
    float* __restrict__ out) {
    __shared__ float red[2048];
    const int i0 = ((int)blockIdx.x >> 4) * 32, j0 = ((int)blockIdx.x & 15) * 32;
    float val[2]; int row[2], col[2];
    tile32(Xhi, Xlo, M, Bh, Bl, M, 512, i0, j0, threadIdx.x, red, val, row, col);
    #pragma unroll
    for (int e = 0; e < 2; ++e)
        out[(size_t)row[e] * M + col[e]] = val[e];
}

extern "C" void kernel_launch(void* const* d_in, const int* in_sizes, int n_in,
                              void* d_out, int out_size, void* d_ws, size_t ws_size,
                              hipStream_t stream) {
    const float* Xin = (const float*)d_in[0];
    float* out = (float*)d_out;
    u16* w = (u16*)d_ws;

    u16* Xhi = w;                      // D*M = 1048576 u16 each
    u16* Xlo = w + 1048576u;
    u16* X1h = w + 2097152u;
    u16* X1l = w + 3145728u;
    u16* X2h = w + 4194304u;
    u16* X2l = w + 5242880u;
    u16* q = w + 6291456u;             // M*M = 262144 u16 each below
    u16* G0h = q;            u16* G0l = q + 262144u;
    u16* C1h = q + 524288u;  u16* C1l = q + 786432u;
    u16* Sh  = q + 1048576u; u16* Sl  = q + 1310720u;
    u16* G1h = q + 1572864u; u16* G1l = q + 1835008u;
    u16* C2h = q + 2097152u; u16* C2l = q + 2359296u;
    u16* S1h = q + 2621440u; u16* S1l = q + 2883584u;
    u16* C3h = q + 3145728u; u16* C3l = q + 3407872u;

    // d1: fused transpose + gram: G0, C1 = CA1 I - CB1 G0, Xhi/Xlo
    gram_fx<<<256, 512, 0, stream>>>(Xin, G0h, G0l, C1h, C1l, Xhi, Xlo);
    // d2: S = G0^2  ||  X1 = X·C1
    dualSX<<<1280, 512, 0, stream>>>(G0h, G0l, Sh, Sl,
                                     Xhi, Xlo, C1h, C1l, X1h, X1l);
    // d3: G1 = CA1^2 G0 - 2 CA1 CB1 S + CB1^2 (G0·S); C2 = CA2 I - CB2 G1
    poly32<<<256, 512, 0, stream>>>(G0h, G0l, Sh, Sl, G0h, G0l, Sh, Sl,
                                    G1h, G1l, C2h, C2l,
                                    CA1 * CA1, -2.0f * CA1 * CB1, CB1 * CB1,
                                    CA2, CB2, 1);
    // d4: S1 = G1^2  ||  X2 = X1·C2
    dualSX<<<1280, 512, 0, stream>>>(G1h, G1l, S1h, S1l,
                                     X1h, X1l, C2h, C2l, X2h, X2l);
    // d5: G2-poly -> C3 only
    poly32<<<256, 512, 0, stream>>>(G1h, G1l, S1h, S1l, G1h, G1l, S1h, S1l,
                                    nullptr, nullptr, C3h, C3l,
                                    CA2 * CA2, -2.0f * CA2 * CB2, CB2 * CB2,
                                    CA3, CB3, 0);
    // d6: out = X2·C3
    xb32<<<1024, 512, 0, stream>>>(X2h, X2l, C3h, C3l, out);
}

// Round 5
// 152.026 us; speedup vs baseline: 1.3050x; 1.3050x over previous
//
#include <hip/hip_runtime.h>

#define D 2048
#define M 512

// Tuned NS coefficients, equioscillation on sv interval [0.48,1.52]:
// step1 -> delta 0.2188, step2 -> 0.03633, step3 -> 0.00099
#define CA1 1.7509363f
#define CB1 0.5353890f
#define CA2 1.5424421f
#define CB2 0.5060067f
#define CA3 1.5011558f
#define CB3 0.5001653f

// P = C1*C2 as quartic in G (commuting polynomial algebra):
// P = PI0*I + PI1*G + PI2*G^2 + PI3*G^3 + PI4*G^4, coefficients all O(1).
#define PI0 (CA1 * CA2)
#define PI1 (-(CA1 * CA1 * CA1 * CB2 + CA2 * CB1))
#define PI2 (3.0f * CA1 * CA1 * CB1 * CB2)
#define PI3 (-3.0f * CA1 * CB1 * CB1 * CB2)
#define PI4 (CB1 * CB1 * CB1 * CB2)

typedef unsigned short u16;
typedef unsigned int u32;
typedef __attribute__((ext_vector_type(8))) short bf16x8;
typedef __attribute__((ext_vector_type(4))) float f32x4;

__device__ inline u16 f2bf(float f) {
    union { float f; unsigned u; } v; v.f = f;
    unsigned r = v.u + 0x7fffu + ((v.u >> 16) & 1u);  // RNE
    return (u16)(r >> 16);
}
__device__ inline float bf2f(u16 h) {
    union { float f; unsigned u; } v; v.u = ((unsigned)h) << 16;
    return v.f;
}

__device__ inline void store_split(u16* __restrict__ H, u16* __restrict__ L,
                                   size_t idx, float v) {
    const u16 h = f2bf(v);
    H[idx] = h;
    L[idx] = f2bf(v - bf2f(h));
}

// One 128-k chunk: load all 16 fragments, then 12 MFMAs.
__device__ inline void mmchunk(const u16* __restrict__ ah, const u16* __restrict__ al,
                               const u16* __restrict__ bh, const u16* __restrict__ bl,
                               f32x4& a1, f32x4& a2) {
    bf16x8 fah[4], fal[4], fbh[4], fbl[4];
    #pragma unroll
    for (int i = 0; i < 4; ++i) {
        fah[i] = *(const bf16x8*)(ah + 32 * i);
        fal[i] = *(const bf16x8*)(al + 32 * i);
        fbh[i] = *(const bf16x8*)(bh + 32 * i);
        fbl[i] = *(const bf16x8*)(bl + 32 * i);
    }
    #pragma unroll
    for (int i = 0; i < 4; ++i) {
        a1 = __builtin_amdgcn_mfma_f32_16x16x32_bf16(fah[i], fbh[i], a1, 0, 0, 0);
        a2 = __builtin_amdgcn_mfma_f32_16x16x32_bf16(fah[i], fbl[i], a2, 0, 0, 0);
        a2 = __builtin_amdgcn_mfma_f32_16x16x32_bf16(fal[i], fbh[i], a2, 0, 0, 0);
    }
}

// per-wave K-range fragment MACs (K multiple of 128)
__device__ inline void mm_ks(const u16* __restrict__ aHi,
                             const u16* __restrict__ aLo, int lda,
                             const u16* __restrict__ bHi,
                             const u16* __restrict__ bLo, int ldb,
                             int K, int lm, int lq, f32x4& a1, f32x4& a2) {
    const u16* ah = aHi + (size_t)lm * lda + lq * 8;
    const u16* al = aLo + (size_t)lm * lda + lq * 8;
    const u16* bh = bHi + (size_t)lm * ldb + lq * 8;
    const u16* bl = bLo + (size_t)lm * ldb + lq * 8;
    #pragma unroll 4
    for (int k = 0; k < K; k += 128)
        mmchunk(ah + k, al + k, bh + k, bl + k, a1, a2);
}

// 32x32 tile of U·V^T per 512-thread block: 8 waves = 4 quadrants x 2 K-halves.
__device__ inline void tile32(const u16* __restrict__ Uh, const u16* __restrict__ Ul, int lda,
                              const u16* __restrict__ Vh, const u16* __restrict__ Vl, int ldb,
                              int K, int i0, int j0, int t, float* red,
                              float val[2], int row[2], int col[2]) {
    const int w = t >> 6, lane = t & 63;
    const int lm = lane & 15, lq = lane >> 4;
    const int q = w >> 1, kh = w & 1;
    const int qi = q >> 1, qj = q & 1;
    const int Kh = K >> 1;
    const size_t ko = (size_t)kh * Kh;
    f32x4 a1 = {0.f, 0.f, 0.f, 0.f}, a2 = {0.f, 0.f, 0.f, 0.f};
    mm_ks(Uh + (size_t)(i0 + 16 * qi) * lda + ko, Ul + (size_t)(i0 + 16 * qi) * lda + ko, lda,
          Vh + (size_t)(j0 + 16 * qj) * ldb + ko, Vl + (size_t)(j0 + 16 * qj) * ldb + ko, ldb,
          Kh, lm, lq, a1, a2);
    const f32x4 s = a1 + a2;
    #pragma unroll
    for (int r = 0; r < 4; ++r) red[w * 256 + (lq * 4 + r) * 16 + lm] = s[r];
    __syncthreads();
    #pragma unroll
    for (int e = 0; e < 2; ++e) {
        const int ee = t + e * 512;
        const int qq = ee >> 8, p = ee & 255;
        val[e] = red[qq * 512 + p] + red[qq * 512 + 256 + p];
        row[e] = i0 + 16 * (qq >> 1) + (p >> 4);
        col[e] = j0 + 16 * (qq & 1) + (p & 15);
    }
}

// LDS swizzle for the fused gram staging
__device__ inline int swz(int c) { return (((c >> 2) ^ c) & 3) << 3; }

// ---- d1: fused transpose + gram: G0 = X^T X from X fp32 directly.
// 256 blocks x 512 thr. 128-k chunks, LDS transposed [c][k^swz(c)] double
// buffered (64 KB). j0==0 blocks also emit Xhi/Xlo row-major.
// Emits G0 hi/lo and C = CA1*I - CB1*G0 (scratch here, unused downstream).
__global__ __launch_bounds__(512) void gram_fx(
    const float* __restrict__ X,
    u16* __restrict__ Gh, u16* __restrict__ Gl,
    u16* __restrict__ Ch, u16* __restrict__ Cl,
    u16* __restrict__ Xhi, u16* __restrict__ Xlo) {
    __shared__ __align__(16) char smem[65536];
    u32* LT = (u32*)smem;          // 4 regions of 4096 u32: A:buf, B:2+buf
    float* red = (float*)smem;     // reused for the final reduce

    const int i0 = (blockIdx.x >> 4) * 32, j0 = (blockIdx.x & 15) * 32;
    const int t = threadIdx.x;
    const int w = t >> 6, lane = t & 63;
    const int lm = lane & 15, lq = lane >> 4;
    const int q = w >> 1, kh = w & 1;
    const int qi = q >> 1, qj = q & 1;
    const bool emitX = (j0 == 0);

    const int r = t >> 3;            // 0..63 (k within chunk, +64 for 2nd row)
    const int c4 = (t & 7) * 4;      // 0..28 (col within stripe)

    const float* pa = X + (size_t)r * M + i0 + c4;
    const float* pb = X + (size_t)r * M + j0 + c4;
    float4 fA0 = *(const float4*)pa;
    float4 fA1 = *(const float4*)(pa + (size_t)64 * M);
    float4 fB0 = *(const float4*)pb;
    float4 fB1 = *(const float4*)(pb + (size_t)64 * M);

    f32x4 a1 = {0.f, 0.f, 0.f, 0.f}, a2 = {0.f, 0.f, 0.f, 0.f};
    int buf = 0;

    for (int k0 = 0; k0 < D; k0 += 128) {
        u32 pkA0[4], pkA1[4], pkB0[4], pkB1[4];
        {
            const float va0[4] = {fA0.x, fA0.y, fA0.z, fA0.w};
            const float va1[4] = {fA1.x, fA1.y, fA1.z, fA1.w};
            const float vb0[4] = {fB0.x, fB0.y, fB0.z, fB0.w};
            const float vb1[4] = {fB1.x, fB1.y, fB1.z, fB1.w};
            #pragma unroll
            for (int e = 0; e < 4; ++e) {
                union { float f; u32 u; } u0, u1, u2, u3, h0, h1, h2, h3;
                u0.f = va0[e]; u1.f = va1[e]; u2.f = vb0[e]; u3.f = vb1[e];
                h0.u = u0.u & 0xFFFF0000u;  // truncated hi
                h1.u = u1.u & 0xFFFF0000u;
                h2.u = u2.u & 0xFFFF0000u;
                h3.u = u3.u & 0xFFFF0000u;
                pkA0[e] = h0.u | f2bf(va0[e] - h0.f);
                pkA1[e] = h1.u | f2bf(va1[e] - h1.f);
                pkB0[e] = h2.u | f2bf(vb0[e] - h2.f);
                pkB1[e] = h3.u | f2bf(vb1[e] - h3.f);
            }
        }
        u32* A0 = LT + buf * 4096;
        u32* B0 = LT + (2 + buf) * 4096;
        #pragma unroll
        for (int e = 0; e < 4; ++e) {
            const int c = c4 + e;
            const int rk = r ^ swz(c);
            A0[c * 128 + rk] = pkA0[e];
            A0[c * 128 + rk + 64] = pkA1[e];
            B0[c * 128 + rk] = pkB0[e];
            B0[c * 128 + rk + 64] = pkB1[e];
        }
        if (emitX) {  // row-major bf16 split of X (this block's stripe)
            uint2 hw, lw;
            hw.x = (pkA0[0] >> 16) | (pkA0[1] & 0xFFFF0000u);
            hw.y = (pkA0[2] >> 16) | (pkA0[3] & 0xFFFF0000u);
            lw.x = (pkA0[0] & 0xFFFFu) | (pkA0[1] << 16);
            lw.y = (pkA0[2] & 0xFFFFu) | (pkA0[3] << 16);
            *(uint2*)(Xhi + (size_t)(k0 + r) * M + i0 + c4) = hw;
            *(uint2*)(Xlo + (size_t)(k0 + r) * M + i0 + c4) = lw;
            hw.x = (pkA1[0] >> 16) | (pkA1[1] & 0xFFFF0000u);
            hw.y = (pkA1[2] >> 16) | (pkA1[3] & 0xFFFF0000u);
            lw.x = (pkA1[0] & 0xFFFFu) | (pkA1[1] << 16);
            lw.y = (pkA1[2] & 0xFFFFu) | (pkA1[3] << 16);
            *(uint2*)(Xhi + (size_t)(k0 + r + 64) * M + i0 + c4) = hw;
            *(uint2*)(Xlo + (size_t)(k0 + r + 64) * M + i0 + c4) = lw;
        }
        __syncthreads();
        if (k0 + 128 < D) {
            fA0 = *(const float4*)(pa + (size_t)(k0 + 128) * M);
            fA1 = *(const float4*)(pa + (size_t)(k0 + 192) * M);
            fB0 = *(const float4*)(pb + (size_t)(k0 + 128) * M);
            fB1 = *(const float4*)(pb + (size_t)(k0 + 192) * M);
        }
        #pragma unroll
        for (int ks = 0; ks < 64; ks += 32) {
            const int ca = 16 * qi + lm, cb = 16 * qj + lm;
            const int kb = kh * 64 + ks + lq * 8;
            const u32* ap = A0 + ca * 128 + (kb ^ swz(ca));
            const u32* bp = B0 + cb * 128 + (kb ^ swz(cb));
            u32 au[8], bu[8];
            *(uint4*)(au) = *(const uint4*)(ap);
            *(uint4*)(au + 4) = *(const uint4*)(ap + 4);
            *(uint4*)(bu) = *(const uint4*)(bp);
            *(uint4*)(bu + 4) = *(const uint4*)(bp + 4);
            u32 ahp[4], alp[4], bhp[4], blp[4];
            #pragma unroll
            for (int e = 0; e < 4; ++e) {
                ahp[e] = (au[2 * e] >> 16) | (au[2 * e + 1] & 0xFFFF0000u);
                alp[e] = (au[2 * e] & 0xFFFFu) | (au[2 * e + 1] << 16);
                bhp[e] = (bu[2 * e] >> 16) | (bu[2 * e + 1] & 0xFFFF0000u);
                blp[e] = (bu[2 * e] & 0xFFFFu) | (bu[2 * e + 1] << 16);
            }
            const bf16x8 fah = *(const bf16x8*)ahp;
            const bf16x8 fal = *(const bf16x8*)alp;
            const bf16x8 fbh = *(const bf16x8*)bhp;
            const bf16x8 fbl = *(const bf16x8*)blp;
            a1 = __builtin_amdgcn_mfma_f32_16x16x32_bf16(fah, fbh, a1, 0, 0, 0);
            a2 = __builtin_amdgcn_mfma_f32_16x16x32_bf16(fah, fbl, a2, 0, 0, 0);
            a2 = __builtin_amdgcn_mfma_f32_16x16x32_bf16(fal, fbh, a2, 0, 0, 0);
        }
        buf ^= 1;
    }

    __syncthreads();
    const f32x4 s = a1 + a2;
    #pragma unroll
    for (int e = 0; e < 4; ++e) red[w * 256 + (lq * 4 + e) * 16 + lm] = s[e];
    __syncthreads();
    #pragma unroll
    for (int e = 0; e < 2; ++e) {
        const int ee = t + e * 512;
        const int qq = ee >> 8, p = ee & 255;
        const float g = red[qq * 512 + p] + red[qq * 512 + 256 + p];
        const int row = i0 + 16 * (qq >> 1) + (p >> 4);
        const int col = j0 + 16 * (qq & 1) + (p & 15);
        const size_t idx = (size_t)row * M + col;
        u16 h = f2bf(g);
        Gh[idx] = h; Gl[idx] = f2bf(g - bf2f(h));
        const float c = (row == col ? CA1 : 0.0f) - CB1 * g;
        h = f2bf(c);
        Ch[idx] = h; Cl[idx] = f2bf(c - bf2f(h));
    }
}

// ---- plain M-space mm: O = U·V^T. grid 256 x 512 thr, 32x32 tile/block.
__global__ __launch_bounds__(512) void mm32(
    const u16* __restrict__ Uh, const u16* __restrict__ Ul,
    const u16* __restrict__ Vh, const u16* __restrict__ Vl,
    u16* __restrict__ Oh, u16* __restrict__ Ol) {
    __shared__ float red[2048];
    const int i0 = ((int)blockIdx.x >> 4) * 32, j0 = ((int)blockIdx.x & 15) * 32;
    float val[2]; int row[2], col[2];
    tile32(Uh, Ul, M, Vh, Vl, M, 512, i0, j0, threadIdx.x, red, val, row, col);
    #pragma unroll
    for (int e = 0; e < 2; ++e)
        store_split(Oh, Ol, (size_t)row[e] * M + col[e], val[e]);
}

// ---- powp: fused G3 = G·S and G4 = S·S (two acc pairs, shared B-operand),
// epilogue P = PI0·I + PI1·G + PI2·S + PI3·G3 + PI4·G4 (fp32 internal powers,
// only tame P is stored). 256 blocks x 512 thr, tile32 geometry.
__global__ __launch_bounds__(512) void powp(
    const u16* __restrict__ Gh, const u16* __restrict__ Gl,
    const u16* __restrict__ Sh, const u16* __restrict__ Sl,
    u16* __restrict__ Ph, u16* __restrict__ Pl) {
    __shared__ float red[2048];
    const int i0 = ((int)blockIdx.x >> 4) * 32, j0 = ((int)blockIdx.x & 15) * 32;
    const int t = threadIdx.x, w = t >> 6, lane = t & 63;
    const int lm = lane & 15, lq = lane >> 4;
    const int q = w >> 1, kh = w & 1;
    const int qi = q >> 1, qj = q & 1;
    const size_t ko = (size_t)kh * 256;
    const u16* agh = Gh + (size_t)(i0 + 16 * qi + lm) * M + ko + lq * 8;
    const u16* agl = Gl + (size_t)(i0 + 16 * qi + lm) * M + ko + lq * 8;
    const u16* ash = Sh + (size_t)(i0 + 16 * qi + lm) * M + ko + lq * 8;
    const u16* asl = Sl + (size_t)(i0 + 16 * qi + lm) * M + ko + lq * 8;
    const u16* bsh = Sh + (size_t)(j0 + 16 * qj + lm) * M + ko + lq * 8;
    const u16* bsl = Sl + (size_t)(j0 + 16 * qj + lm) * M + ko + lq * 8;
    f32x4 g1 = {0.f, 0.f, 0.f, 0.f}, g2 = {0.f, 0.f, 0.f, 0.f};
    f32x4 u1 = {0.f, 0.f, 0.f, 0.f}, u2 = {0.f, 0.f, 0.f, 0.f};
    #pragma unroll 8
    for (int k = 0; k < 256; k += 32) {
        const bf16x8 fgh = *(const bf16x8*)(agh + k);
        const bf16x8 fgl = *(const bf16x8*)(agl + k);
        const bf16x8 fsh = *(const bf16x8*)(ash + k);
        const bf16x8 fsl = *(const bf16x8*)(asl + k);
        const bf16x8 fbh = *(const bf16x8*)(bsh + k);
        const bf16x8 fbl = *(const bf16x8*)(bsl + k);
        g1 = __builtin_amdgcn_mfma_f32_16x16x32_bf16(fgh, fbh, g1, 0, 0, 0);
        g2 = __builtin_amdgcn_mfma_f32_16x16x32_bf16(fgh, fbl, g2, 0, 0, 0);
        g2 = __builtin_amdgcn_mfma_f32_16x16x32_bf16(fgl, fbh, g2, 0, 0, 0);
        u1 = __builtin_amdgcn_mfma_f32_16x16x32_bf16(fsh, fbh, u1, 0, 0, 0);
        u2 = __builtin_amdgcn_mfma_f32_16x16x32_bf16(fsh, fbl, u2, 0, 0, 0);
        u2 = __builtin_amdgcn_mfma_f32_16x16x32_bf16(fsl, fbh, u2, 0, 0, 0);
    }
    // reduce acc3 (G·S)
    const f32x4 s3 = g1 + g2;
    #pragma unroll
    for (int r = 0; r < 4; ++r) red[w * 256 + (lq * 4 + r) * 16 + lm] = s3[r];
    __syncthreads();
    float val3[2]; int row[2], col[2];
    #pragma unroll
    for (int e = 0; e < 2; ++e) {
        const int ee = t + e * 512;
        const int qq = ee >> 8, p = ee & 255;
        val3[e] = red[qq * 512 + p] + red[qq * 512 + 256 + p];
        row[e] = i0 + 16 * (qq >> 1) + (p >> 4);
        col[e] = j0 + 16 * (qq & 1) + (p & 15);
    }
    __syncthreads();
    // reduce acc4 (S·S)
    const f32x4 s4 = u1 + u2;
    #pragma unroll
    for (int r = 0; r < 4; ++r) red[w * 256 + (lq * 4 + r) * 16 + lm] = s4[r];
    __syncthreads();
    #pragma unroll
    for (int e = 0; e < 2; ++e) {
        const int ee = t + e * 512;
        const int qq = ee >> 8, p = ee & 255;
        const float val4 = red[qq * 512 + p] + red[qq * 512 + 256 + p];
        const size_t idx = (size_t)row[e] * M + col[e];
        const float g = bf2f(Gh[idx]) + bf2f(Gl[idx]);
        const float s = bf2f(Sh[idx]) + bf2f(Sl[idx]);
        const float pv = PI1 * g + PI2 * s + PI3 * val3[e] + PI4 * val4
                       + (row[e] == col[e] ? PI0 : 0.0f);
        store_split(Ph, Pl, idx, pv);
    }
}

// ---- dual M-space mm: job0: O0=U0·V0^T, job1: O1=U1·V1^T. grid 512 x 512 thr.
__global__ __launch_bounds__(512) void dual32(
    const u16* __restrict__ U0h, const u16* __restrict__ U0l,
    const u16* __restrict__ V0h, const u16* __restrict__ V0l,
    u16* __restrict__ O0h, u16* __restrict__ O0l,
    const u16* __restrict__ U1h, const u16* __restrict__ U1l,
    const u16* __restrict__ V1h, const u16* __restrict__ V1l,
    u16* __restrict__ O1h, u16* __restrict__ O1l) {
    __shared__ float red[2048];
    const int job = (int)blockIdx.x >> 8, tile = (int)blockIdx.x & 255;
    const int i0 = (tile >> 4) * 32, j0 = (tile & 15) * 32;
    const u16* Uh = job ? U1h : U0h;
    const u16* Ul = job ? U1l : U0l;
    const u16* Vh = job ? V1h : V0h;
    const u16* Vl = job ? V1l : V0l;
    u16* Oh = job ? O1h : O0h;
    u16* Ol = job ? O1l : O0l;
    float val[2]; int row[2], col[2];
    tile32(Uh, Ul, M, Vh, Vl, M, 512, i0, j0, threadIdx.x, red, val, row, col);
    #pragma unroll
    for (int e = 0; e < 2; ++e)
        store_split(Oh, Ol, (size_t)row[e] * M + col[e], val[e]);
}

// ---- poly step: W=U·V^T; P = cA*Ge + cB*Se + cC*W; store P (opt),
// C = a*I - b*P (opt). grid 256 x 512 thr.
__global__ __launch_bounds__(512) void poly32(
    const u16* __restrict__ Uh, const u16* __restrict__ Ul,
    const u16* __restrict__ Vh, const u16* __restrict__ Vl,
    const u16* __restrict__ Geh, const u16* __restrict__ Gel,
    const u16* __restrict__ Seh, const u16* __restrict__ Sel,
    u16* __restrict__ Ph, u16* __restrict__ Pl,
    u16* __restrict__ Ch, u16* __restrict__ Cl,
    const float cA, const float cB, const float cC,
    const float a, const float b, const int writeP, const int writeC) {
    __shared__ float red[2048];
    const int i0 = ((int)blockIdx.x >> 4) * 32, j0 = ((int)blockIdx.x & 15) * 32;
    float val[2]; int row[2], col[2];
    tile32(Uh, Ul, M, Vh, Vl, M, 512, i0, j0, threadIdx.x, red, val, row, col);
    #pragma unroll
    for (int e = 0; e < 2; ++e) {
        const size_t idx = (size_t)row[e] * M + col[e];
        const float p = cA * (bf2f(Geh[idx]) + bf2f(Gel[idx]))
                      + cB * (bf2f(Seh[idx]) + bf2f(Sel[idx]))
                      + cC * val[e];
        if (writeP) {
            store_split(Ph, Pl, idx, p);
        }
        if (writeC) {
            const float c = (row[e] == col[e] ? a : 0.0f) - b * p;
            store_split(Ch, Cl, idx, c);
        }
    }
}

// ---- final: out = X·B^T (fp32). 32x32 tile/block, 4 full-K quadrant waves.
__global__ __launch_bounds__(256) void final32(
    const u16* __restrict__ Xhi, const u16* __restrict__ Xlo,
    const u16* __restrict__ Bh, const u16* __restrict__ Bl,
    float* __restrict__ out) {
    const int t = threadIdx.x;
    const int i0 = ((int)blockIdx.x >> 4) * 32, j0 = ((int)blockIdx.x & 15) * 32;
    const int w = t >> 6, lane = t & 63;
    const int lm = lane & 15, lq = lane >> 4;
    const int qi = w >> 1, qj = w & 1;
    f32x4 a1 = {0.f, 0.f, 0.f, 0.f}, a2 = {0.f, 0.f, 0.f, 0.f};
    mm_ks(Xhi + (size_t)(i0 + 16 * qi) * M, Xlo + (size_t)(i0 + 16 * qi) * M, M,
          Bh + (size_t)(j0 + 16 * qj) * M, Bl + (size_t)(j0 + 16 * qj) * M, M,
          512, lm, lq, a1, a2);
    const f32x4 acc = a1 + a2;
    float* o = out + (size_t)(i0 + 16 * qi + lq * 4) * M + j0 + 16 * qj + lm;
    #pragma unroll
    for (int r = 0; r < 4; ++r) o[(size_t)r * M] = acc[r];
}

extern "C" void kernel_launch(void* const* d_in, const int* in_sizes, int n_in,
                              void* d_out, int out_size, void* d_ws, size_t ws_size,
                              hipStream_t stream) {
    const float* Xin = (const float*)d_in[0];
    float* out = (float*)d_out;
    u16* w = (u16*)d_ws;

    u16* Xhi = w;                      // D*M = 1048576 u16 each
    u16* Xlo = w + 1048576u;
    u16* q = w + 2097152u;             // M*M = 262144 u16 each below
    u16* G0h = q;            u16* G0l = q + 262144u;
    u16* Csh = q + 524288u;  u16* Csl = q + 786432u;   // scratch (gram's C out)
    u16* Sh  = q + 1048576u; u16* Sl  = q + 1310720u;
    u16* Ph  = q + 1572864u; u16* Pl  = q + 1835008u;
    u16* Th  = q + 2097152u; u16* Tl  = q + 2359296u;
    u16* Qh  = q + 2621440u; u16* Ql  = q + 2883584u;
    u16* Bh  = q + 3145728u; u16* Bl  = q + 3407872u;

    // d1: fused transpose + gram: G0 (C-out is scratch), Xhi/Xlo
    gram_fx<<<256, 512, 0, stream>>>(Xin, G0h, G0l, Csh, Csl, Xhi, Xlo);
    // d2: S = G0^2
    mm32<<<256, 512, 0, stream>>>(G0h, G0l, G0h, G0l, Sh, Sl);
    // d3: P = C1·C2 = PI0 I + PI1 G + PI2 S + PI3 (G·S) + PI4 (S·S)
    powp<<<256, 512, 0, stream>>>(G0h, G0l, Sh, Sl, Ph, Pl);
    // d4: T = P^2  ||  Q = P·G0
    dual32<<<512, 512, 0, stream>>>(Ph, Pl, Ph, Pl, Th, Tl,
                                    Ph, Pl, G0h, G0l, Qh, Ql);
    // d5: B = CA3·P - CB3·(T·Q)   [= P·C3]
    poly32<<<256, 512, 0, stream>>>(Th, Tl, Qh, Ql, Ph, Pl, Ph, Pl,
                                    Bh, Bl, Csh, Csl,
                                    CA3, 0.0f, -CB3,
                                    0.0f, 0.0f, 1, 0);
    // d6: out = X·B
    final32<<<1024, 256, 0, stream>>>(Xhi, Xlo, Bh, Bl, out);
}

// Round 6
// 150.876 us; speedup vs baseline: 1.3149x; 1.0076x over previous
//
#include <hip/hip_runtime.h>

#define D 2048
#define M 512

// Tuned NS coefficients, equioscillation on sv interval [0.48,1.52]:
// step1 -> delta 0.2188, step2 -> 0.03633, step3 -> 0.00099
#define CA1 1.7509363f
#define CB1 0.5353890f
#define CA2 1.5424421f
#define CB2 0.5060067f
#define CA3 1.5011558f
#define CB3 0.5001653f

// P = C1*C2 as quartic in G (commuting polynomial algebra):
// P = PI0*I + PI1*G + PI2*G^2 + PI3*G^3 + PI4*G^4, coefficients all O(1).
#define PI0 (CA1 * CA2)
#define PI1 (-(CA1 * CA1 * CA1 * CB2 + CA2 * CB1))
#define PI2 (3.0f * CA1 * CA1 * CB1 * CB2)
#define PI3 (-3.0f * CA1 * CB1 * CB1 * CB2)
#define PI4 (CB1 * CB1 * CB1 * CB2)

typedef unsigned short u16;
typedef unsigned int u32;
typedef __attribute__((ext_vector_type(8))) short bf16x8;
typedef __attribute__((ext_vector_type(4))) float f32x4;

__device__ inline u16 f2bf(float f) {
    union { float f; unsigned u; } v; v.f = f;
    unsigned r = v.u + 0x7fffu + ((v.u >> 16) & 1u);  // RNE
    return (u16)(r >> 16);
}
__device__ inline float bf2f(u16 h) {
    union { float f; unsigned u; } v; v.u = ((unsigned)h) << 16;
    return v.f;
}

__device__ inline void store_split(u16* __restrict__ H, u16* __restrict__ L,
                                   size_t idx, float v) {
    const u16 h = f2bf(v);
    H[idx] = h;
    L[idx] = f2bf(v - bf2f(h));
}

// One 128-k chunk: load all 16 fragments, then 12 MFMAs.
__device__ inline void mmchunk(const u16* __restrict__ ah, const u16* __restrict__ al,
                               const u16* __restrict__ bh, const u16* __restrict__ bl,
                               f32x4& a1, f32x4& a2) {
    bf16x8 fah[4], fal[4], fbh[4], fbl[4];
    #pragma unroll
    for (int i = 0; i < 4; ++i) {
        fah[i] = *(const bf16x8*)(ah + 32 * i);
        fal[i] = *(const bf16x8*)(al + 32 * i);
        fbh[i] = *(const bf16x8*)(bh + 32 * i);
        fbl[i] = *(const bf16x8*)(bl + 32 * i);
    }
    #pragma unroll
    for (int i = 0; i < 4; ++i) {
        a1 = __builtin_amdgcn_mfma_f32_16x16x32_bf16(fah[i], fbh[i], a1, 0, 0, 0);
        a2 = __builtin_amdgcn_mfma_f32_16x16x32_bf16(fah[i], fbl[i], a2, 0, 0, 0);
        a2 = __builtin_amdgcn_mfma_f32_16x16x32_bf16(fal[i], fbh[i], a2, 0, 0, 0);
    }
}

// per-wave K-range fragment MACs (K multiple of 128)
__device__ inline void mm_ks(const u16* __restrict__ aHi,
                             const u16* __restrict__ aLo, int lda,
                             const u16* __restrict__ bHi,
                             const u16* __restrict__ bLo, int ldb,
                             int K, int lm, int lq, f32x4& a1, f32x4& a2) {
    const u16* ah = aHi + (size_t)lm * lda + lq * 8;
    const u16* al = aLo + (size_t)lm * lda + lq * 8;
    const u16* bh = bHi + (size_t)lm * ldb + lq * 8;
    const u16* bl = bLo + (size_t)lm * ldb + lq * 8;
    #pragma unroll 4
    for (int k = 0; k < K; k += 128)
        mmchunk(ah + k, al + k, bh + k, bl + k, a1, a2);
}

// 32x32 tile of U·V^T per 512-thread block: 8 waves = 4 quadrants x 2 K-halves.
__device__ inline void tile32(const u16* __restrict__ Uh, const u16* __restrict__ Ul, int lda,
                              const u16* __restrict__ Vh, const u16* __restrict__ Vl, int ldb,
                              int K, int i0, int j0, int t, float* red,
                              float val[2], int row[2], int col[2]) {
    const int w = t >> 6, lane = t & 63;
    const int lm = lane & 15, lq = lane >> 4;
    const int q = w >> 1, kh = w & 1;
    const int qi = q >> 1, qj = q & 1;
    const int Kh = K >> 1;
    const size_t ko = (size_t)kh * Kh;
    f32x4 a1 = {0.f, 0.f, 0.f, 0.f}, a2 = {0.f, 0.f, 0.f, 0.f};
    mm_ks(Uh + (size_t)(i0 + 16 * qi) * lda + ko, Ul + (size_t)(i0 + 16 * qi) * lda + ko, lda,
          Vh + (size_t)(j0 + 16 * qj) * ldb + ko, Vl + (size_t)(j0 + 16 * qj) * ldb + ko, ldb,
          Kh, lm, lq, a1, a2);
    const f32x4 s = a1 + a2;
    #pragma unroll
    for (int r = 0; r < 4; ++r) red[w * 256 + (lq * 4 + r) * 16 + lm] = s[r];
    __syncthreads();
    #pragma unroll
    for (int e = 0; e < 2; ++e) {
        const int ee = t + e * 512;
        const int qq = ee >> 8, p = ee & 255;
        val[e] = red[qq * 512 + p] + red[qq * 512 + 256 + p];
        row[e] = i0 + 16 * (qq >> 1) + (p >> 4);
        col[e] = j0 + 16 * (qq & 1) + (p & 15);
    }
}

// LDS swizzle for the fused gram staging
__device__ inline int swz(int c) { return (((c >> 2) ^ c) & 3) << 3; }

// ---- d1: fused transpose + gram: G0 = X^T X from X fp32 directly.
// 256 blocks x 512 thr. 128-k chunks, LDS transposed [c][k^swz(c)] double
// buffered (64 KB). XCD-chunk swizzle: each XCD owns a 4x8 tile block
// (i-stripes + j-stripes ~3 MB < 4 MiB L2). X-emission spread evenly:
// block (it,jt) emits k-chunk jt of i-stripe it (16 KB/block, balanced).
// Emits G0 hi/lo and C = CA1*I - CB1*G0 (scratch here, unused downstream).
__global__ __launch_bounds__(512) void gram_fx(
    const float* __restrict__ X,
    u16* __restrict__ Gh, u16* __restrict__ Gl,
    u16* __restrict__ Ch, u16* __restrict__ Cl,
    u16* __restrict__ Xhi, u16* __restrict__ Xlo) {
    __shared__ __align__(16) char smem[65536];
    u32* LT = (u32*)smem;          // 4 regions of 4096 u32: A:buf, B:2+buf
    float* red = (float*)smem;     // reused for the final reduce

    // XCD-aware tile assignment: xcd = bid&7 owns i-tiles [4a,4a+4),
    // j-tiles [8b,8b+8) with a=xcd>>1, b=xcd&1 (bijective digit remap).
    const int bb = (int)blockIdx.x;
    const int r8 = bb >> 3, xcd = bb & 7;
    const int it = (xcd >> 1) * 4 + (r8 >> 3);
    const int jt = (xcd & 1) * 8 + (r8 & 7);
    const int i0 = it * 32, j0 = jt * 32;
    const int t = threadIdx.x;
    const int w = t >> 6, lane = t & 63;
    const int lm = lane & 15, lq = lane >> 4;
    const int q = w >> 1, kh = w & 1;
    const int qi = q >> 1, qj = q & 1;

    const int r = t >> 3;            // 0..63 (k within chunk, +64 for 2nd row)
    const int c4 = (t & 7) * 4;      // 0..28 (col within stripe)

    const float* pa = X + (size_t)r * M + i0 + c4;
    const float* pb = X + (size_t)r * M + j0 + c4;
    float4 fA0 = *(const float4*)pa;
    float4 fA1 = *(const float4*)(pa + (size_t)64 * M);
    float4 fB0 = *(const float4*)pb;
    float4 fB1 = *(const float4*)(pb + (size_t)64 * M);

    f32x4 a1 = {0.f, 0.f, 0.f, 0.f}, a2 = {0.f, 0.f, 0.f, 0.f};
    int buf = 0;

    for (int k0 = 0; k0 < D; k0 += 128) {
        u32 pkA0[4], pkA1[4], pkB0[4], pkB1[4];
        {
            const float va0[4] = {fA0.x, fA0.y, fA0.z, fA0.w};
            const float va1[4] = {fA1.x, fA1.y, fA1.z, fA1.w};
            const float vb0[4] = {fB0.x, fB0.y, fB0.z, fB0.w};
            const float vb1[4] = {fB1.x, fB1.y, fB1.z, fB1.w};
            #pragma unroll
            for (int e = 0; e < 4; ++e) {
                union { float f; u32 u; } u0, u1, u2, u3, h0, h1, h2, h3;
                u0.f = va0[e]; u1.f = va1[e]; u2.f = vb0[e]; u3.f = vb1[e];
                h0.u = u0.u & 0xFFFF0000u;  // truncated hi
                h1.u = u1.u & 0xFFFF0000u;
                h2.u = u2.u & 0xFFFF0000u;
                h3.u = u3.u & 0xFFFF0000u;
                pkA0[e] = h0.u | f2bf(va0[e] - h0.f);
                pkA1[e] = h1.u | f2bf(va1[e] - h1.f);
                pkB0[e] = h2.u | f2bf(vb0[e] - h2.f);
                pkB1[e] = h3.u | f2bf(vb1[e] - h3.f);
            }
        }
        u32* A0 = LT + buf * 4096;
        u32* B0 = LT + (2 + buf) * 4096;
        #pragma unroll
        for (int e = 0; e < 4; ++e) {
            const int c = c4 + e;
            const int rk = r ^ swz(c);
            A0[c * 128 + rk] = pkA0[e];
            A0[c * 128 + rk + 64] = pkA1[e];
            B0[c * 128 + rk] = pkB0[e];
            B0[c * 128 + rk + 64] = pkB1[e];
        }
        if ((k0 >> 7) == jt) {  // balanced X-emission: this block's k-chunk
            uint2 hw, lw;
            hw.x = (pkA0[0] >> 16) | (pkA0[1] & 0xFFFF0000u);
            hw.y = (pkA0[2] >> 16) | (pkA0[3] & 0xFFFF0000u);
            lw.x = (pkA0[0] & 0xFFFFu) | (pkA0[1] << 16);
            lw.y = (pkA0[2] & 0xFFFFu) | (pkA0[3] << 16);
            *(uint2*)(Xhi + (size_t)(k0 + r) * M + i0 + c4) = hw;
            *(uint2*)(Xlo + (size_t)(k0 + r) * M + i0 + c4) = lw;
            hw.x = (pkA1[0] >> 16) | (pkA1[1] & 0xFFFF0000u);
            hw.y = (pkA1[2] >> 16) | (pkA1[3] & 0xFFFF0000u);
            lw.x = (pkA1[0] & 0xFFFFu) | (pkA1[1] << 16);
            lw.y = (pkA1[2] & 0xFFFFu) | (pkA1[3] << 16);
            *(uint2*)(Xhi + (size_t)(k0 + r + 64) * M + i0 + c4) = hw;
            *(uint2*)(Xlo + (size_t)(k0 + r + 64) * M + i0 + c4) = lw;
        }
        __syncthreads();
        if (k0 + 128 < D) {
            fA0 = *(const float4*)(pa + (size_t)(k0 + 128) * M);
            fA1 = *(const float4*)(pa + (size_t)(k0 + 192) * M);
            fB0 = *(const float4*)(pb + (size_t)(k0 + 128) * M);
            fB1 = *(const float4*)(pb + (size_t)(k0 + 192) * M);
        }
        #pragma unroll
        for (int ks = 0; ks < 64; ks += 32) {
            const int ca = 16 * qi + lm, cb = 16 * qj + lm;
            const int kb = kh * 64 + ks + lq * 8;
            const u32* ap = A0 + ca * 128 + (kb ^ swz(ca));
            const u32* bp = B0 + cb * 128 + (kb ^ swz(cb));
            u32 au[8], bu[8];
            *(uint4*)(au) = *(const uint4*)(ap);
            *(uint4*)(au + 4) = *(const uint4*)(ap + 4);
            *(uint4*)(bu) = *(const uint4*)(bp);
            *(uint4*)(bu + 4) = *(const uint4*)(bp + 4);
            u32 ahp[4], alp[4], bhp[4], blp[4];
            #pragma unroll
            for (int e = 0; e < 4; ++e) {
                ahp[e] = (au[2 * e] >> 16) | (au[2 * e + 1] & 0xFFFF0000u);
                alp[e] = (au[2 * e] & 0xFFFFu) | (au[2 * e + 1] << 16);
                bhp[e] = (bu[2 * e] >> 16) | (bu[2 * e + 1] & 0xFFFF0000u);
                blp[e] = (bu[2 * e] & 0xFFFFu) | (bu[2 * e + 1] << 16);
            }
            const bf16x8 fah = *(const bf16x8*)ahp;
            const bf16x8 fal = *(const bf16x8*)alp;
            const bf16x8 fbh = *(const bf16x8*)bhp;
            const bf16x8 fbl = *(const bf16x8*)blp;
            a1 = __builtin_amdgcn_mfma_f32_16x16x32_bf16(fah, fbh, a1, 0, 0, 0);
            a2 = __builtin_amdgcn_mfma_f32_16x16x32_bf16(fah, fbl, a2, 0, 0, 0);
            a2 = __builtin_amdgcn_mfma_f32_16x16x32_bf16(fal, fbh, a2, 0, 0, 0);
        }
        buf ^= 1;
    }

    __syncthreads();
    const f32x4 s = a1 + a2;
    #pragma unroll
    for (int e = 0; e < 4; ++e) red[w * 256 + (lq * 4 + e) * 16 + lm] = s[e];
    __syncthreads();
    #pragma unroll
    for (int e = 0; e < 2; ++e) {
        const int ee = t + e * 512;
        const int qq = ee >> 8, p = ee & 255;
        const float g = red[qq * 512 + p] + red[qq * 512 + 256 + p];
        const int row = i0 + 16 * (qq >> 1) + (p >> 4);
        const int col = j0 + 16 * (qq & 1) + (p & 15);
        const size_t idx = (size_t)row * M + col;
        u16 h = f2bf(g);
        Gh[idx] = h; Gl[idx] = f2bf(g - bf2f(h));
        const float c = (row == col ? CA1 : 0.0f) - CB1 * g;
        h = f2bf(c);
        Ch[idx] = h; Cl[idx] = f2bf(c - bf2f(h));
    }
}

// ---- plain M-space mm: O = U·V^T. grid 256 x 512 thr, 32x32 tile/block.
__global__ __launch_bounds__(512) void mm32(
    const u16* __restrict__ Uh, const u16* __restrict__ Ul,
    const u16* __restrict__ Vh, const u16* __restrict__ Vl,
    u16* __restrict__ Oh, u16* __restrict__ Ol) {
    __shared__ float red[2048];
    const int i0 = ((int)blockIdx.x >> 4) * 32, j0 = ((int)blockIdx.x & 15) * 32;
    float val[2]; int row[2], col[2];
    tile32(Uh, Ul, M, Vh, Vl, M, 512, i0, j0, threadIdx.x, red, val, row, col);
    #pragma unroll
    for (int e = 0; e < 2; ++e)
        store_split(Oh, Ol, (size_t)row[e] * M + col[e], val[e]);
}

// ---- powp: fused G3 = G·S and G4 = S·S (two acc pairs, shared B-operand),
// epilogue P = PI0·I + PI1·G + PI2·S + PI3·G3 + PI4·G4 (fp32 internal powers,
// only tame P is stored). 256 blocks x 512 thr, tile32 geometry.
__global__ __launch_bounds__(512) void powp(
    const u16* __restrict__ Gh, const u16* __restrict__ Gl,
    const u16* __restrict__ Sh, const u16* __restrict__ Sl,
    u16* __restrict__ Ph, u16* __restrict__ Pl) {
    __shared__ float red[2048];
    const int i0 = ((int)blockIdx.x >> 4) * 32, j0 = ((int)blockIdx.x & 15) * 32;
    const int t = threadIdx.x, w = t >> 6, lane = t & 63;
    const int lm = lane & 15, lq = lane >> 4;
    const int q = w >> 1, kh = w & 1;
    const int qi = q >> 1, qj = q & 1;
    const size_t ko = (size_t)kh * 256;
    const u16* agh = Gh + (size_t)(i0 + 16 * qi + lm) * M + ko + lq * 8;
    const u16* agl = Gl + (size_t)(i0 + 16 * qi + lm) * M + ko + lq * 8;
    const u16* ash = Sh + (size_t)(i0 + 16 * qi + lm) * M + ko + lq * 8;
    const u16* asl = Sl + (size_t)(i0 + 16 * qi + lm) * M + ko + lq * 8;
    const u16* bsh = Sh + (size_t)(j0 + 16 * qj + lm) * M + ko + lq * 8;
    const u16* bsl = Sl + (size_t)(j0 + 16 * qj + lm) * M + ko + lq * 8;
    f32x4 g1 = {0.f, 0.f, 0.f, 0.f}, g2 = {0.f, 0.f, 0.f, 0.f};
    f32x4 u1 = {0.f, 0.f, 0.f, 0.f}, u2 = {0.f, 0.f, 0.f, 0.f};
    #pragma unroll 8
    for (int k = 0; k < 256; k += 32) {
        const bf16x8 fgh = *(const bf16x8*)(agh + k);
        const bf16x8 fgl = *(const bf16x8*)(agl + k);
        const bf16x8 fsh = *(const bf16x8*)(ash + k);
        const bf16x8 fsl = *(const bf16x8*)(asl + k);
        const bf16x8 fbh = *(const bf16x8*)(bsh + k);
        const bf16x8 fbl = *(const bf16x8*)(bsl + k);
        g1 = __builtin_amdgcn_mfma_f32_16x16x32_bf16(fgh, fbh, g1, 0, 0, 0);
        g2 = __builtin_amdgcn_mfma_f32_16x16x32_bf16(fgh, fbl, g2, 0, 0, 0);
        g2 = __builtin_amdgcn_mfma_f32_16x16x32_bf16(fgl, fbh, g2, 0, 0, 0);
        u1 = __builtin_amdgcn_mfma_f32_16x16x32_bf16(fsh, fbh, u1, 0, 0, 0);
        u2 = __builtin_amdgcn_mfma_f32_16x16x32_bf16(fsh, fbl, u2, 0, 0, 0);
        u2 = __builtin_amdgcn_mfma_f32_16x16x32_bf16(fsl, fbh, u2, 0, 0, 0);
    }
    // reduce acc3 (G·S)
    const f32x4 s3 = g1 + g2;
    #pragma unroll
    for (int r = 0; r < 4; ++r) red[w * 256 + (lq * 4 + r) * 16 + lm] = s3[r];
    __syncthreads();
    float val3[2]; int row[2], col[2];
    #pragma unroll
    for (int e = 0; e < 2; ++e) {
        const int ee = t + e * 512;
        const int qq = ee >> 8, p = ee & 255;
        val3[e] = red[qq * 512 + p] + red[qq * 512 + 256 + p];
        row[e] = i0 + 16 * (qq >> 1) + (p >> 4);
        col[e] = j0 + 16 * (qq & 1) + (p & 15);
    }
    __syncthreads();
    // reduce acc4 (S·S)
    const f32x4 s4 = u1 + u2;
    #pragma unroll
    for (int r = 0; r < 4; ++r) red[w * 256 + (lq * 4 + r) * 16 + lm] = s4[r];
    __syncthreads();
    #pragma unroll
    for (int e = 0; e < 2; ++e) {
        const int ee = t + e * 512;
        const int qq = ee >> 8, p = ee & 255;
        const float val4 = red[qq * 512 + p] + red[qq * 512 + 256 + p];
        const size_t idx = (size_t)row[e] * M + col[e];
        const float g = bf2f(Gh[idx]) + bf2f(Gl[idx]);
        const float s = bf2f(Sh[idx]) + bf2f(Sl[idx]);
        const float pv = PI1 * g + PI2 * s + PI3 * val3[e] + PI4 * val4
                       + (row[e] == col[e] ? PI0 : 0.0f);
        store_split(Ph, Pl, idx, pv);
    }
}

// ---- dual M-space mm: job0: O0=U0·V0^T, job1: O1=U1·V1^T. grid 512 x 512 thr.
__global__ __launch_bounds__(512) void dual32(
    const u16* __restrict__ U0h, const u16* __restrict__ U0l,
    const u16* __restrict__ V0h, const u16* __restrict__ V0l,
    u16* __restrict__ O0h, u16* __restrict__ O0l,
    const u16* __restrict__ U1h, const u16* __restrict__ U1l,
    const u16* __restrict__ V1h, const u16* __restrict__ V1l,
    u16* __restrict__ O1h, u16* __restrict__ O1l) {
    __shared__ float red[2048];
    const int job = (int)blockIdx.x >> 8, tile = (int)blockIdx.x & 255;
    const int i0 = (tile >> 4) * 32, j0 = (tile & 15) * 32;
    const u16* Uh = job ? U1h : U0h;
    const u16* Ul = job ? U1l : U0l;
    const u16* Vh = job ? V1h : V0h;
    const u16* Vl = job ? V1l : V0l;
    u16* Oh = job ? O1h : O0h;
    u16* Ol = job ? O1l : O0l;
    float val[2]; int row[2], col[2];
    tile32(Uh, Ul, M, Vh, Vl, M, 512, i0, j0, threadIdx.x, red, val, row, col);
    #pragma unroll
    for (int e = 0; e < 2; ++e)
        store_split(Oh, Ol, (size_t)row[e] * M + col[e], val[e]);
}

// ---- poly step: W=U·V^T; P = cA*Ge + cB*Se + cC*W; store P (opt),
// C = a*I - b*P (opt). grid 256 x 512 thr.
__global__ __launch_bounds__(512) void poly32(
    const u16* __restrict__ Uh, const u16* __restrict__ Ul,
    const u16* __restrict__ Vh, const u16* __restrict__ Vl,
    const u16* __restrict__ Geh, const u16* __restrict__ Gel,
    const u16* __restrict__ Seh, const u16* __restrict__ Sel,
    u16* __restrict__ Ph, u16* __restrict__ Pl,
    u16* __restrict__ Ch, u16* __restrict__ Cl,
    const float cA, const float cB, const float cC,
    const float a, const float b, const int writeP, const int writeC) {
    __shared__ float red[2048];
    const int i0 = ((int)blockIdx.x >> 4) * 32, j0 = ((int)blockIdx.x & 15) * 32;
    float val[2]; int row[2], col[2];
    tile32(Uh, Ul, M, Vh, Vl, M, 512, i0, j0, threadIdx.x, red, val, row, col);
    #pragma unroll
    for (int e = 0; e < 2; ++e) {
        const size_t idx = (size_t)row[e] * M + col[e];
        const float p = cA * (bf2f(Geh[idx]) + bf2f(Gel[idx]))
                      + cB * (bf2f(Seh[idx]) + bf2f(Sel[idx]))
                      + cC * val[e];
        if (writeP) {
            store_split(Ph, Pl, idx, p);
        }
        if (writeC) {
            const float c = (row[e] == col[e] ? a : 0.0f) - b * p;
            store_split(Ch, Cl, idx, c);
        }
    }
}

// ---- final: out = X·B^T (fp32). 32x32 tile/block, 4 full-K quadrant waves.
// XCD-chunk swizzle: xcd = bid&7 owns i-tiles [8k,8k+8) x all 16 j-tiles ->
// per-XCD working set = 0.5 MB X-rows + 1 MB B, fully L2-resident.
__global__ __launch_bounds__(256) void final32(
    const u16* __restrict__ Xhi, const u16* __restrict__ Xlo,
    const u16* __restrict__ Bh, const u16* __restrict__ Bl,
    float* __restrict__ out) {
    const int t = threadIdx.x;
    const int bid = (int)blockIdx.x;
    const int sw = (bid & 7) * 128 + (bid >> 3);   // bijective digit swap
    const int i0 = (sw >> 4) * 32, j0 = (sw & 15) * 32;
    const int w = t >> 6, lane = t & 63;
    const int lm = lane & 15, lq = lane >> 4;
    const int qi = w >> 1, qj = w & 1;
    f32x4 a1 = {0.f, 0.f, 0.f, 0.f}, a2 = {0.f, 0.f, 0.f, 0.f};
    mm_ks(Xhi + (size_t)(i0 + 16 * qi) * M, Xlo + (size_t)(i0 + 16 * qi) * M, M,
          Bh + (size_t)(j0 + 16 * qj) * M, Bl + (size_t)(j0 + 16 * qj) * M, M,
          512, lm, lq, a1, a2);
    const f32x4 acc = a1 + a2;
    float* o = out + (size_t)(i0 + 16 * qi + lq * 4) * M + j0 + 16 * qj + lm;
    #pragma unroll
    for (int r = 0; r < 4; ++r) o[(size_t)r * M] = acc[r];
}

extern "C" void kernel_launch(void* const* d_in, const int* in_sizes, int n_in,
                              void* d_out, int out_size, void* d_ws, size_t ws_size,
                              hipStream_t stream) {
    const float* Xin = (const float*)d_in[0];
    float* out = (float*)d_out;
    u16* w = (u16*)d_ws;

    u16* Xhi = w;                      // D*M = 1048576 u16 each
    u16* Xlo = w + 1048576u;
    u16* q = w + 2097152u;             // M*M = 262144 u16 each below
    u16* G0h = q;            u16* G0l = q + 262144u;
    u16* Csh = q + 524288u;  u16* Csl = q + 786432u;   // scratch (gram's C out)
    u16* Sh  = q + 1048576u; u16* Sl  = q + 1310720u;
    u16* Ph  = q + 1572864u; u16* Pl  = q + 1835008u;
    u16* Th  = q + 2097152u; u16* Tl  = q + 2359296u;
    u16* Qh  = q + 2621440u; u16* Ql  = q + 2883584u;
    u16* Bh  = q + 3145728u; u16* Bl  = q + 3407872u;

    // d1: fused transpose + gram: G0 (C-out is scratch), Xhi/Xlo
    gram_fx<<<256, 512, 0, stream>>>(Xin, G0h, G0l, Csh, Csl, Xhi, Xlo);
    // d2: S = G0^2
    mm32<<<256, 512, 0, stream>>>(G0h, G0l, G0h, G0l, Sh, Sl);
    // d3: P = C1·C2 = PI0 I + PI1 G + PI2 S + PI3 (G·S) + PI4 (S·S)
    powp<<<256, 512, 0, stream>>>(G0h, G0l, Sh, Sl, Ph, Pl);
    // d4: T = P^2  ||  Q = P·G0
    dual32<<<512, 512, 0, stream>>>(Ph, Pl, Ph, Pl, Th, Tl,
                                    Ph, Pl, G0h, G0l, Qh, Ql);
    // d5: B = CA3·P - CB3·(T·Q)   [= P·C3]
    poly32<<<256, 512, 0, stream>>>(Th, Tl, Qh, Ql, Ph, Pl, Ph, Pl,
                                    Bh, Bl, Csh, Csl,
                                    CA3, 0.0f, -CB3,
                                    0.0f, 0.0f, 1, 0);
    // d6: out = X·B
    final32<<<1024, 256, 0, stream>>>(Xhi, Xlo, Bh, Bl, out);
}